// Round 3
// baseline (3122.922 us; speedup 1.0000x reference)
//
#include <hip/hip_runtime.h>
#include <hip/hip_fp16.h>

#define N_GRAPHS 512
#define NB 1563        // ceil(100000/64) buckets of 64 dst nodes
#define KNODE 64
#define CAP 3072       // bucket capacity; mean 2048, sigma ~45 -> huge margin
#define EPW 8192       // edges per partition workgroup

// ---------------- edge partition: bucket by dst>>6, packed src|dl ----------------

__global__ void k_part(const int* __restrict__ src, const int* __restrict__ dst,
                       int* __restrict__ gCnt, unsigned* __restrict__ ebuf, int E) {
    __shared__ unsigned sh[NB];
    int t = threadIdx.x;
    int e0 = blockIdx.x * EPW;
    int cnt = E - e0 < EPW ? E - e0 : EPW;
    for (int i = t; i < NB; i += 256) sh[i] = 0;
    __syncthreads();
    for (int i = t; i < cnt; i += 256) {
        int d = dst[e0 + i];
        atomicAdd(&sh[d >> 6], 1u);
    }
    __syncthreads();
    for (int b = t; b < NB; b += 256) {
        unsigned c = sh[b];
        unsigned base = c ? (unsigned)atomicAdd(&gCnt[b], (int)c) : 0u;
        sh[b] = (unsigned)b * CAP + base;
    }
    __syncthreads();
    for (int i = t; i < cnt; i += 256) {
        int d = dst[e0 + i];
        int s = src[e0 + i];
        int bkt = d >> 6;
        unsigned dl = (unsigned)(d & 63);
        unsigned pos = atomicAdd(&sh[bkt], 1u);
        if (pos < (unsigned)(bkt + 1) * CAP)
            ebuf[pos] = (unsigned)s | (dl << 20);
    }
}

// ---------------- per-bucket degree -> dinv ----------------

__global__ void k_bdeg(const unsigned* __restrict__ ebuf, const int* __restrict__ gCnt,
                       float* __restrict__ dinv, int n) {
    __shared__ int deg[KNODE];
    int b = blockIdx.x, t = threadIdx.x;
    if (t < KNODE) deg[t] = 0;
    __syncthreads();
    int cnt = gCnt[b];
    if (cnt > CAP) cnt = CAP;
    const unsigned* eb = ebuf + (size_t)b * CAP;
    for (int i = t; i < cnt; i += 256) atomicAdd(&deg[eb[i] >> 20], 1);
    __syncthreads();
    int node = b * KNODE + t;
    if (t < KNODE && node < n) dinv[node] = rsqrtf((float)(deg[t] + 1));
}

// ---------------- dense transforms (fp16 features, f32 accumulate) ----------------

__global__ void k_transform1(const float* __restrict__ x, const float* __restrict__ W,
                             const float* __restrict__ dinv, __half2* __restrict__ ts, int n) {
    __shared__ float2 sW2[3 * 16];
    int t = threadIdx.x;
    for (int i = t; i < 3 * 16; i += blockDim.x) {
        int c = i / 16, j = i % 16;
        sW2[i] = make_float2(W[c * 32 + 2 * j], W[c * 32 + 2 * j + 1]);
    }
    __syncthreads();
    int tid = blockIdx.x * blockDim.x + t;
    int node = tid >> 4;
    int j = tid & 15;
    if (node >= n) return;
    float a0 = x[(size_t)node * 3 + 0];
    float a1 = x[(size_t)node * 3 + 1];
    float a2 = x[(size_t)node * 3 + 2];
    float2 w0 = sW2[0 * 16 + j], w1 = sW2[1 * 16 + j], w2 = sW2[2 * 16 + j];
    float d = dinv[node];
    float rx = d * (a0 * w0.x + a1 * w1.x + a2 * w2.x);
    float ry = d * (a0 * w0.y + a1 * w1.y + a2 * w2.y);
    ts[(size_t)node * 16 + j] = __floats2half2_rn(rx, ry);
}

template <int IN, int OUT>
__global__ void k_transformH(const __half2* __restrict__ act, const float* __restrict__ W,
                             const float* __restrict__ dinv, __half2* __restrict__ ts, int n) {
    const int IN2 = IN / 2, OUT2 = OUT / 2;
    __shared__ float2 sW2[IN * OUT2];
    int t = threadIdx.x;
    for (int i = t; i < IN * OUT2; i += blockDim.x) {
        int c = i / OUT2, j = i % OUT2;
        sW2[i] = make_float2(W[c * OUT + 2 * j], W[c * OUT + 2 * j + 1]);
    }
    __syncthreads();
    int tid = blockIdx.x * blockDim.x + t;
    int node = tid / OUT2;
    int j = tid % OUT2;
    if (node >= n) return;
    const __half2* a = act + (size_t)node * IN2;
    float2 acc = make_float2(0.f, 0.f);
#pragma unroll
    for (int c2 = 0; c2 < IN2; ++c2) {
        float2 av = __half22float2(a[c2]);
        float2 w0 = sW2[(2 * c2) * OUT2 + j];
        float2 w1 = sW2[(2 * c2 + 1) * OUT2 + j];
        acc.x += av.x * w0.x + av.y * w1.x;
        acc.y += av.x * w0.y + av.y * w1.y;
    }
    float d = dinv[node];
    ts[(size_t)node * OUT2 + j] = __floats2half2_rn(d * acc.x, d * acc.y);
}

// ---------------- bucket aggregation with LDS f32 accumulators ----------------
// out[d] = dinv[d]*(ts[d] + sum_s ts[s]) + b ; DIM2 = feature-dim/2 half2 lanes

template <int DIM2, bool RELU>
__global__ void k_aggB(const __half2* __restrict__ ts, const unsigned* __restrict__ ebuf,
                       const int* __restrict__ gCnt, const float* __restrict__ dinv,
                       const float* __restrict__ bias, __half2* __restrict__ out, int n) {
    const int NG = 256 / DIM2;  // edge groups per workgroup
    __shared__ float acc[KNODE * DIM2 * 2];
    int b = blockIdx.x;
    int t = threadIdx.x;
    int lane = t % DIM2;
    int g = t / DIM2;
    int nodeBase = b * KNODE;

    // init accumulators with the self-loop term ts[node]
    for (int i = t; i < KNODE * DIM2; i += 256) {
        int node = nodeBase + i / DIM2;
        float2 v = (node < n) ? __half22float2(ts[(size_t)nodeBase * DIM2 + i])
                              : make_float2(0.f, 0.f);
        acc[2 * i] = v.x;
        acc[2 * i + 1] = v.y;
    }
    __syncthreads();

    int cnt = gCnt[b];
    if (cnt > CAP) cnt = CAP;
    const unsigned* eb = ebuf + (size_t)b * CAP;

    int k = g;
    for (; k + 3 * NG < cnt; k += 4 * NG) {
        unsigned p0 = eb[k], p1 = eb[k + NG], p2 = eb[k + 2 * NG], p3 = eb[k + 3 * NG];
        float2 v0 = __half22float2(ts[(size_t)(p0 & 0xFFFFFu) * DIM2 + lane]);
        float2 v1 = __half22float2(ts[(size_t)(p1 & 0xFFFFFu) * DIM2 + lane]);
        float2 v2 = __half22float2(ts[(size_t)(p2 & 0xFFFFFu) * DIM2 + lane]);
        float2 v3 = __half22float2(ts[(size_t)(p3 & 0xFFFFFu) * DIM2 + lane]);
        int d0 = (p0 >> 20) * DIM2 + lane;
        int d1 = (p1 >> 20) * DIM2 + lane;
        int d2 = (p2 >> 20) * DIM2 + lane;
        int d3 = (p3 >> 20) * DIM2 + lane;
        atomicAdd(&acc[2 * d0], v0.x); atomicAdd(&acc[2 * d0 + 1], v0.y);
        atomicAdd(&acc[2 * d1], v1.x); atomicAdd(&acc[2 * d1 + 1], v1.y);
        atomicAdd(&acc[2 * d2], v2.x); atomicAdd(&acc[2 * d2 + 1], v2.y);
        atomicAdd(&acc[2 * d3], v3.x); atomicAdd(&acc[2 * d3 + 1], v3.y);
    }
    for (; k < cnt; k += NG) {
        unsigned p = eb[k];
        float2 v = __half22float2(ts[(size_t)(p & 0xFFFFFu) * DIM2 + lane]);
        int d = (p >> 20) * DIM2 + lane;
        atomicAdd(&acc[2 * d], v.x);
        atomicAdd(&acc[2 * d + 1], v.y);
    }
    __syncthreads();

    const float2* bias2 = (const float2*)bias;
    for (int i = t; i < KNODE * DIM2; i += 256) {
        int node = nodeBase + i / DIM2;
        if (node >= n) continue;
        float dd = dinv[node];
        float2 bb = bias2[i % DIM2];
        float rx = dd * acc[2 * i] + bb.x;
        float ry = dd * acc[2 * i + 1] + bb.y;
        if (RELU) { rx = fmaxf(rx, 0.f); ry = fmaxf(ry, 0.f); }
        out[(size_t)nodeBase * DIM2 + i] = __floats2half2_rn(rx, ry);
    }
}

// ---------------- pooling over sorted batch (h fp16 [N,32] half2) ----------------

__global__ void k_pool(const __half2* __restrict__ h, const int* __restrict__ batch,
                       float* __restrict__ pooled, int n) {
    const int NBK = 32;
    int lane = threadIdx.x & 31;
    int sub = threadIdx.x >> 5;
    int n0 = (blockIdx.x * 8 + sub) * NBK;
    if (n0 >= n) return;
    int nend = n0 + NBK < n ? n0 + NBK : n;
    float2 acc = make_float2(0.f, 0.f);
    int gcur = batch[n0];
    for (int i = n0; i < nend; ++i) {
        int g = batch[i];
        if (g != gcur) {
            atomicAdd(&pooled[gcur * 64 + 2 * lane], acc.x);
            atomicAdd(&pooled[gcur * 64 + 2 * lane + 1], acc.y);
            acc = make_float2(0.f, 0.f);
            gcur = g;
        }
        float2 v = __half22float2(h[(size_t)i * 32 + lane]);
        acc.x += v.x;
        acc.y += v.y;
    }
    atomicAdd(&pooled[gcur * 64 + 2 * lane], acc.x);
    atomicAdd(&pooled[gcur * 64 + 2 * lane + 1], acc.y);
}

// ---------------- MLP head ----------------

__global__ void k_mlp(const float* __restrict__ pooled, const float* __restrict__ lW1,
                      const float* __restrict__ lb1, const float* __restrict__ lW2,
                      const float* __restrict__ lb2, float* __restrict__ z) {
    __shared__ float sW1[64 * 32], sW2[32 * 5], sb1[32], sb2[5];
    int t = threadIdx.x;
    for (int i = t; i < 64 * 32; i += blockDim.x) sW1[i] = lW1[i];
    for (int i = t; i < 32 * 5; i += blockDim.x) sW2[i] = lW2[i];
    if (t < 32) sb1[t] = lb1[t];
    if (t < 5) sb2[t] = lb2[t];
    __syncthreads();
    int g = blockIdx.x * blockDim.x + t;
    if (g >= N_GRAPHS) return;
    float p[64];
#pragma unroll
    for (int i = 0; i < 64; ++i) p[i] = pooled[g * 64 + i];
    float t1[32];
#pragma unroll
    for (int j = 0; j < 32; ++j) {
        float a = sb1[j];
#pragma unroll
        for (int i = 0; i < 64; ++i) a += p[i] * sW1[i * 32 + j];
        t1[j] = fmaxf(a, 0.f);
    }
#pragma unroll
    for (int c = 0; c < 5; ++c) {
        float a = sb2[c];
#pragma unroll
        for (int i = 0; i < 32; ++i) a += t1[i] * sW2[i * 5 + c];
        z[g * 5 + c] = a;
    }
}

__global__ void k_logsoftmax(const float* __restrict__ z, float* __restrict__ out) {
    __shared__ float red[512];
    int g = threadIdx.x;
#pragma unroll
    for (int c = 0; c < 5; ++c) {
        float v = z[g * 5 + c];
        red[g] = v;
        __syncthreads();
        for (int off = 256; off > 0; off >>= 1) {
            if (g < off) red[g] = fmaxf(red[g], red[g + off]);
            __syncthreads();
        }
        float m = red[0];
        __syncthreads();
        red[g] = expf(v - m);
        __syncthreads();
        for (int off = 256; off > 0; off >>= 1) {
            if (g < off) red[g] += red[g + off];
            __syncthreads();
        }
        float lse = m + logf(red[0]);
        __syncthreads();
        out[g * 5 + c] = v - lse;
    }
}

// ---------------- launch ----------------

extern "C" void kernel_launch(void* const* d_in, const int* in_sizes, int n_in,
                              void* d_out, int out_size, void* d_ws, size_t ws_size,
                              hipStream_t stream) {
    const float* x   = (const float*)d_in[0];
    const int* ei    = (const int*)d_in[1];
    const int* batch = (const int*)d_in[2];
    const float* W1  = (const float*)d_in[3];
    const float* b1  = (const float*)d_in[4];
    const float* W2  = (const float*)d_in[5];
    const float* b2  = (const float*)d_in[6];
    const float* W3  = (const float*)d_in[7];
    const float* b3  = (const float*)d_in[8];
    const float* lW1 = (const float*)d_in[9];
    const float* lb1 = (const float*)d_in[10];
    const float* lW2 = (const float*)d_in[11];
    const float* lb2 = (const float*)d_in[12];

    const int N = in_sizes[0] / 3;   // 100000
    const int E = in_sizes[1] / 2;   // 3200000
    const int* src = ei;
    const int* dst = ei + E;

    char* ws = (char*)d_ws;
    size_t off = 0;
    auto alloc = [&](size_t bytes) -> void* {
        void* p = ws + off;
        off = (off + bytes + 255) & ~(size_t)255;
        return p;
    };

    int*      gCnt   = (int*)alloc((size_t)NB * 4);
    float*    dinv   = (float*)alloc((size_t)N * 4);
    unsigned* ebuf   = (unsigned*)alloc((size_t)NB * CAP * 4);
    __half2*  bufT   = (__half2*)alloc((size_t)N * 32 * 4);
    __half2*  bufH   = (__half2*)alloc((size_t)N * 32 * 4);
    float*    pooled = (float*)alloc((size_t)N_GRAPHS * 64 * 4);
    float*    z      = (float*)alloc((size_t)N_GRAPHS * 5 * 4);

    hipMemsetAsync(gCnt, 0, (size_t)NB * 4, stream);
    hipMemsetAsync(pooled, 0, (size_t)N_GRAPHS * 64 * 4, stream);

    // partition + degrees
    int nPartWg = (E + EPW - 1) / EPW;
    k_part<<<nPartWg, 256, 0, stream>>>(src, dst, gCnt, ebuf, E);
    k_bdeg<<<NB, 256, 0, stream>>>(ebuf, gCnt, dinv, N);

    // Layer 1: [N,3] -> [N,32], relu
    k_transform1<<<((size_t)N * 16 + 255) / 256, 256, 0, stream>>>(x, W1, dinv, bufT, N);
    k_aggB<16, true><<<NB, 256, 0, stream>>>(bufT, ebuf, gCnt, dinv, b1, bufH, N);
    // Layer 2: [N,32] -> [N,64], relu
    k_transformH<32, 64><<<((size_t)N * 32 + 255) / 256, 256, 0, stream>>>(bufH, W2, dinv, bufT, N);
    k_aggB<32, true><<<NB, 256, 0, stream>>>(bufT, ebuf, gCnt, dinv, b2, bufH, N);
    // Layer 3: [N,64] -> [N,64], no relu
    k_transformH<64, 64><<<((size_t)N * 32 + 255) / 256, 256, 0, stream>>>(bufH, W3, dinv, bufT, N);
    k_aggB<32, false><<<NB, 256, 0, stream>>>(bufT, ebuf, gCnt, dinv, b3, bufH, N);

    // Pool + head
    k_pool<<<(N + 8 * 32 - 1) / (8 * 32), 256, 0, stream>>>(bufH, batch, pooled, N);
    k_mlp<<<2, 256, 0, stream>>>(pooled, lW1, lb1, lW2, lb2, z);
    k_logsoftmax<<<1, 512, 0, stream>>>(z, (float*)d_out);
}

// Round 4
// 540.090 us; speedup vs baseline: 5.7822x; 5.7822x over previous
//
#include <hip/hip_runtime.h>
#include <hip/hip_fp16.h>

#define N_GRAPHS 512
#define NB 1563        // ceil(100000/64) buckets of 64 dst nodes
#define KNODE 64
#define CAP 3072       // bucket capacity; mean 2048, sigma ~45
#define EPW 8192       // edges per partition workgroup
#define NBLK 3125      // ceil(100000/32) node-blocks for aggregation

// ---------------- edge partition: bucket by dst>>6, packed src|dl<<20 ----------------

__global__ void k_part(const int* __restrict__ src, const int* __restrict__ dst,
                       int* __restrict__ gCnt, unsigned* __restrict__ ebuf, int E) {
    __shared__ unsigned pos[NB];
    __shared__ int dstc[EPW];
    int t = threadIdx.x;
    int e0 = blockIdx.x * EPW;
    int cnt = E - e0 < EPW ? E - e0 : EPW;
    for (int i = t; i < NB; i += 256) pos[i] = 0;
    __syncthreads();
    for (int i = t; i < cnt; i += 256) {
        int d = dst[e0 + i];
        dstc[i] = d;
        atomicAdd(&pos[d >> 6], 1u);
    }
    __syncthreads();
    for (int b = t; b < NB; b += 256) {
        unsigned c = pos[b];
        unsigned base = c ? (unsigned)atomicAdd(&gCnt[b], (int)c) : 0u;
        pos[b] = (unsigned)b * CAP + base;
    }
    __syncthreads();
    for (int i = t; i < cnt; i += 256) {
        int d = dstc[i];
        int s = src[e0 + i];
        int bkt = d >> 6;
        unsigned p = atomicAdd(&pos[bkt], 1u);
        if (p < (unsigned)(bkt + 1) * CAP)
            ebuf[p] = (unsigned)s | ((unsigned)(d & 63) << 20);
    }
}

// ---------------- per-bucket counting sort -> CSR rows + dinv (in-place) ----------------

__global__ void k_csr(unsigned* __restrict__ ebuf, const int* __restrict__ gCnt,
                      int2* __restrict__ rows, float* __restrict__ dinv, int n) {
    __shared__ unsigned ec[CAP];
    __shared__ int deg[KNODE];
    __shared__ int pfx[KNODE];
    int b = blockIdx.x, t = threadIdx.x;
    int cnt = gCnt[b];
    if (cnt > CAP) cnt = CAP;
    if (t < KNODE) deg[t] = 0;
    __syncthreads();
    unsigned* eb = ebuf + (size_t)b * CAP;
    for (int i = t; i < cnt; i += 256) {
        unsigned p = eb[i];
        ec[i] = p;
        atomicAdd(&deg[p >> 20], 1);
    }
    __syncthreads();
    if (t == 0) {
        int a = 0;
        for (int i = 0; i < KNODE; ++i) { pfx[i] = a; a += deg[i]; }
    }
    __syncthreads();
    if (t < KNODE) {
        int node = b * KNODE + t;
        if (node < n) {
            rows[node] = make_int2(b * CAP + pfx[t], deg[t]);
            dinv[node] = rsqrtf((float)(deg[t] + 1));
        }
    }
    if (t < KNODE) deg[t] = pfx[t];  // reuse as cursors
    __syncthreads();
    for (int i = t; i < cnt; i += 256) {
        unsigned p = ec[i];
        int pp = atomicAdd(&deg[p >> 20], 1);
        eb[pp] = p & 0xFFFFFu;  // sorted by dst-local, src only
    }
}

// ---------------- dense transforms: slice-major fp16 output [chunk][N][8 half2] ----------------

__global__ void k_transform1(const float* __restrict__ x, const float* __restrict__ W,
                             const float* __restrict__ dinv, __half2* __restrict__ ts, int n) {
    __shared__ float2 sW2[3 * 16];
    int t = threadIdx.x;
    for (int i = t; i < 3 * 16; i += blockDim.x) {
        int c = i / 16, j = i % 16;
        sW2[i] = make_float2(W[c * 32 + 2 * j], W[c * 32 + 2 * j + 1]);
    }
    __syncthreads();
    int tid = blockIdx.x * blockDim.x + t;
    int node = tid >> 4;
    int j = tid & 15;
    if (node >= n) return;
    float a0 = x[(size_t)node * 3 + 0];
    float a1 = x[(size_t)node * 3 + 1];
    float a2 = x[(size_t)node * 3 + 2];
    float2 w0 = sW2[0 * 16 + j], w1 = sW2[1 * 16 + j], w2 = sW2[2 * 16 + j];
    float d = dinv[node];
    float rx = d * (a0 * w0.x + a1 * w1.x + a2 * w2.x);
    float ry = d * (a0 * w0.y + a1 * w1.y + a2 * w2.y);
    ts[((size_t)(j >> 3) * n + node) * 8 + (j & 7)] = __floats2half2_rn(rx, ry);
}

template <int IN, int OUT>
__global__ void k_transformH(const __half2* __restrict__ act, const float* __restrict__ W,
                             const float* __restrict__ dinv, __half2* __restrict__ ts, int n) {
    const int IN2 = IN / 2, OUT2 = OUT / 2;
    __shared__ float2 sW2[IN * OUT2];
    int t = threadIdx.x;
    for (int i = t; i < IN * OUT2; i += blockDim.x) {
        int c = i / OUT2, j = i % OUT2;
        sW2[i] = make_float2(W[c * OUT + 2 * j], W[c * OUT + 2 * j + 1]);
    }
    __syncthreads();
    int tid = blockIdx.x * blockDim.x + t;
    int node = tid / OUT2;
    int j = tid % OUT2;
    if (node >= n) return;
    float2 acc = make_float2(0.f, 0.f);
#pragma unroll
    for (int c2 = 0; c2 < IN2; ++c2) {
        float2 av = __half22float2(act[((size_t)(c2 >> 3) * n + node) * 8 + (c2 & 7)]);
        float2 w0 = sW2[(2 * c2) * OUT2 + j];
        float2 w1 = sW2[(2 * c2 + 1) * OUT2 + j];
        acc.x += av.x * w0.x + av.y * w1.x;
        acc.y += av.x * w0.y + av.y * w1.y;
    }
    float d = dinv[node];
    ts[((size_t)(j >> 3) * n + node) * 8 + (j & 7)] = __floats2half2_rn(d * acc.x, d * acc.y);
}

// ---------------- sliced aggregation: slice pinned to XCD via blockIdx%8 ----------------
// out[d] = dinv[d]*(ts[d] + sum_s ts[s]) + b   per 16-feature slice (8 half2 lanes)

template <int NSLICE, bool RELU>
__global__ void k_aggS(const __half2* __restrict__ ts, const unsigned* __restrict__ esrc,
                       const int2* __restrict__ rows, const float* __restrict__ dinv,
                       const float* __restrict__ bias, __half2* __restrict__ out, int n) {
    const int XPG = 8 / NSLICE;  // XCDs per slice
    int i = blockIdx.x;
    int xcd = i & 7;
    int slice = xcd % NSLICE;
    int nb = (i >> 3) * XPG + xcd / NSLICE;
    if (nb >= NBLK) return;
    int t = threadIdx.x;
    int lane = t & 7;
    int grp = t >> 3;            // 0..31 nodes per block
    int node = nb * 32 + grp;
    if (node >= n) return;
    const __half2* tss = ts + (size_t)slice * n * 8;
    int2 rc = rows[node];
    float2 acc = __half22float2(tss[(size_t)node * 8 + lane]);  // self-loop
    int start = rc.x, cnt = rc.y;
    int e = 0;
    for (; e + 4 <= cnt; e += 4) {
        unsigned s0 = __builtin_nontemporal_load(&esrc[start + e + 0]);
        unsigned s1 = __builtin_nontemporal_load(&esrc[start + e + 1]);
        unsigned s2 = __builtin_nontemporal_load(&esrc[start + e + 2]);
        unsigned s3 = __builtin_nontemporal_load(&esrc[start + e + 3]);
        float2 v0 = __half22float2(tss[(size_t)s0 * 8 + lane]);
        float2 v1 = __half22float2(tss[(size_t)s1 * 8 + lane]);
        float2 v2 = __half22float2(tss[(size_t)s2 * 8 + lane]);
        float2 v3 = __half22float2(tss[(size_t)s3 * 8 + lane]);
        acc.x += v0.x + v1.x + v2.x + v3.x;
        acc.y += v0.y + v1.y + v2.y + v3.y;
    }
    for (; e < cnt; ++e) {
        unsigned s = __builtin_nontemporal_load(&esrc[start + e]);
        float2 v = __half22float2(tss[(size_t)s * 8 + lane]);
        acc.x += v.x;
        acc.y += v.y;
    }
    float dd = dinv[node];
    const float2* b2p = (const float2*)bias;
    float2 bb = b2p[slice * 8 + lane];
    float rx = dd * acc.x + bb.x;
    float ry = dd * acc.y + bb.y;
    if (RELU) { rx = fmaxf(rx, 0.f); ry = fmaxf(ry, 0.f); }
    out[((size_t)slice * n + node) * 8 + lane] = __floats2half2_rn(rx, ry);
}

// ---------------- pooling over sorted batch (h slice-major fp16) ----------------

__global__ void k_pool(const __half2* __restrict__ h, const int* __restrict__ batch,
                       float* __restrict__ pooled, int n) {
    const int NBK = 32;
    int lane = threadIdx.x & 31;
    int sub = threadIdx.x >> 5;
    int n0 = (blockIdx.x * 8 + sub) * NBK;
    if (n0 >= n) return;
    int nend = n0 + NBK < n ? n0 + NBK : n;
    int s = lane >> 3, c = lane & 7;
    int fb = s * 16 + 2 * c;
    float2 acc = make_float2(0.f, 0.f);
    int gcur = batch[n0];
    for (int i = n0; i < nend; ++i) {
        int g = batch[i];
        if (g != gcur) {
            atomicAdd(&pooled[gcur * 64 + fb], acc.x);
            atomicAdd(&pooled[gcur * 64 + fb + 1], acc.y);
            acc = make_float2(0.f, 0.f);
            gcur = g;
        }
        float2 v = __half22float2(h[((size_t)s * n + i) * 8 + c]);
        acc.x += v.x;
        acc.y += v.y;
    }
    atomicAdd(&pooled[gcur * 64 + fb], acc.x);
    atomicAdd(&pooled[gcur * 64 + fb + 1], acc.y);
}

// ---------------- MLP head ----------------

__global__ void k_mlp(const float* __restrict__ pooled, const float* __restrict__ lW1,
                      const float* __restrict__ lb1, const float* __restrict__ lW2,
                      const float* __restrict__ lb2, float* __restrict__ z) {
    __shared__ float sW1[64 * 32], sW2[32 * 5], sb1[32], sb2[5];
    int t = threadIdx.x;
    for (int i = t; i < 64 * 32; i += blockDim.x) sW1[i] = lW1[i];
    for (int i = t; i < 32 * 5; i += blockDim.x) sW2[i] = lW2[i];
    if (t < 32) sb1[t] = lb1[t];
    if (t < 5) sb2[t] = lb2[t];
    __syncthreads();
    int g = blockIdx.x * blockDim.x + t;
    if (g >= N_GRAPHS) return;
    float p[64];
#pragma unroll
    for (int i = 0; i < 64; ++i) p[i] = pooled[g * 64 + i];
    float t1[32];
#pragma unroll
    for (int j = 0; j < 32; ++j) {
        float a = sb1[j];
#pragma unroll
        for (int i = 0; i < 64; ++i) a += p[i] * sW1[i * 32 + j];
        t1[j] = fmaxf(a, 0.f);
    }
#pragma unroll
    for (int c = 0; c < 5; ++c) {
        float a = sb2[c];
#pragma unroll
        for (int i = 0; i < 32; ++i) a += t1[i] * sW2[i * 5 + c];
        z[g * 5 + c] = a;
    }
}

__global__ void k_logsoftmax(const float* __restrict__ z, float* __restrict__ out) {
    __shared__ float red[512];
    int g = threadIdx.x;
#pragma unroll
    for (int c = 0; c < 5; ++c) {
        float v = z[g * 5 + c];
        red[g] = v;
        __syncthreads();
        for (int off = 256; off > 0; off >>= 1) {
            if (g < off) red[g] = fmaxf(red[g], red[g + off]);
            __syncthreads();
        }
        float m = red[0];
        __syncthreads();
        red[g] = expf(v - m);
        __syncthreads();
        for (int off = 256; off > 0; off >>= 1) {
            if (g < off) red[g] += red[g + off];
            __syncthreads();
        }
        float lse = m + logf(red[0]);
        __syncthreads();
        out[g * 5 + c] = v - lse;
    }
}

// ---------------- launch ----------------

extern "C" void kernel_launch(void* const* d_in, const int* in_sizes, int n_in,
                              void* d_out, int out_size, void* d_ws, size_t ws_size,
                              hipStream_t stream) {
    const float* x   = (const float*)d_in[0];
    const int* ei    = (const int*)d_in[1];
    const int* batch = (const int*)d_in[2];
    const float* W1  = (const float*)d_in[3];
    const float* b1  = (const float*)d_in[4];
    const float* W2  = (const float*)d_in[5];
    const float* b2  = (const float*)d_in[6];
    const float* W3  = (const float*)d_in[7];
    const float* b3  = (const float*)d_in[8];
    const float* lW1 = (const float*)d_in[9];
    const float* lb1 = (const float*)d_in[10];
    const float* lW2 = (const float*)d_in[11];
    const float* lb2 = (const float*)d_in[12];

    const int N = in_sizes[0] / 3;   // 100000
    const int E = in_sizes[1] / 2;   // 3200000
    const int* src = ei;
    const int* dst = ei + E;

    char* ws = (char*)d_ws;
    size_t off = 0;
    auto alloc = [&](size_t bytes) -> void* {
        void* p = ws + off;
        off = (off + bytes + 255) & ~(size_t)255;
        return p;
    };

    int*      gCnt   = (int*)alloc((size_t)NB * 4);
    float*    dinv   = (float*)alloc((size_t)N * 4);
    int2*     rows   = (int2*)alloc((size_t)N * 8);
    unsigned* ebuf   = (unsigned*)alloc((size_t)NB * CAP * 4);
    __half2*  bufT   = (__half2*)alloc((size_t)N * 32 * 4);
    __half2*  bufH   = (__half2*)alloc((size_t)N * 32 * 4);
    float*    pooled = (float*)alloc((size_t)N_GRAPHS * 64 * 4);
    float*    z      = (float*)alloc((size_t)N_GRAPHS * 5 * 4);

    hipMemsetAsync(gCnt, 0, (size_t)NB * 4, stream);
    hipMemsetAsync(pooled, 0, (size_t)N_GRAPHS * 64 * 4, stream);

    // CSR build via buckets
    int nPartWg = (E + EPW - 1) / EPW;
    k_part<<<nPartWg, 256, 0, stream>>>(src, dst, gCnt, ebuf, E);
    k_csr<<<NB, 256, 0, stream>>>(ebuf, gCnt, rows, dinv, N);

    // Layer 1: [N,3] -> [N,32], relu (2 slices)
    k_transform1<<<((size_t)N * 16 + 255) / 256, 256, 0, stream>>>(x, W1, dinv, bufT, N);
    k_aggS<2, true><<<8 * ((NBLK + 3) / 4), 256, 0, stream>>>(bufT, ebuf, rows, dinv, b1, bufH, N);
    // Layer 2: [N,32] -> [N,64], relu (4 slices)
    k_transformH<32, 64><<<((size_t)N * 32 + 255) / 256, 256, 0, stream>>>(bufH, W2, dinv, bufT, N);
    k_aggS<4, true><<<8 * ((NBLK + 1) / 2), 256, 0, stream>>>(bufT, ebuf, rows, dinv, b2, bufH, N);
    // Layer 3: [N,64] -> [N,64], no relu (4 slices)
    k_transformH<64, 64><<<((size_t)N * 32 + 255) / 256, 256, 0, stream>>>(bufH, W3, dinv, bufT, N);
    k_aggS<4, false><<<8 * ((NBLK + 1) / 2), 256, 0, stream>>>(bufT, ebuf, rows, dinv, b3, bufH, N);

    // Pool + head
    k_pool<<<(N + 8 * 32 - 1) / (8 * 32), 256, 0, stream>>>(bufH, batch, pooled, N);
    k_mlp<<<2, 256, 0, stream>>>(pooled, lW1, lb1, lW2, lb2, z);
    k_logsoftmax<<<1, 512, 0, stream>>>(z, (float*)d_out);
}

// Round 5
// 374.180 us; speedup vs baseline: 8.3460x; 1.4434x over previous
//
#include <hip/hip_runtime.h>
#include <hip/hip_fp16.h>

#define N_GRAPHS 512
#define NB 1563        // ceil(100000/64) buckets of 64 dst nodes
#define KNODE 64
#define CAP 3072       // bucket capacity; mean 2048, sigma ~45
#define EPW 8192       // edges per partition workgroup

// ---------------- edge partition: bucket by dst>>6, packed src|dl<<20 ----------------

__global__ void k_part(const int4* __restrict__ src4, const int4* __restrict__ dst4,
                       int* __restrict__ gCnt, unsigned* __restrict__ ebuf, int E4) {
    __shared__ unsigned pos[NB];
    __shared__ int dstc[EPW];
    int t = threadIdx.x;
    int e0 = blockIdx.x * (EPW / 4);
    int cnt4 = E4 - e0 < EPW / 4 ? E4 - e0 : EPW / 4;
    for (int i = t; i < NB; i += 256) pos[i] = 0;
    __syncthreads();
    for (int i = t; i < cnt4; i += 256) {
        int4 d = dst4[e0 + i];
        dstc[4 * i + 0] = d.x; dstc[4 * i + 1] = d.y;
        dstc[4 * i + 2] = d.z; dstc[4 * i + 3] = d.w;
        atomicAdd(&pos[d.x >> 6], 1u);
        atomicAdd(&pos[d.y >> 6], 1u);
        atomicAdd(&pos[d.z >> 6], 1u);
        atomicAdd(&pos[d.w >> 6], 1u);
    }
    __syncthreads();
    for (int b = t; b < NB; b += 256) {
        unsigned c = pos[b];
        unsigned base = c ? (unsigned)atomicAdd(&gCnt[b], (int)c) : 0u;
        pos[b] = (unsigned)b * CAP + base;
    }
    __syncthreads();
    for (int i = t; i < cnt4; i += 256) {
        int4 s = src4[e0 + i];
#pragma unroll
        for (int q = 0; q < 4; ++q) {
            int d = dstc[4 * i + q];
            int sv = q == 0 ? s.x : q == 1 ? s.y : q == 2 ? s.z : s.w;
            int bkt = d >> 6;
            unsigned p = atomicAdd(&pos[bkt], 1u);
            if (p < (unsigned)(bkt + 1) * CAP)
                ebuf[p] = (unsigned)sv | ((unsigned)(d & 63) << 20);
        }
    }
}

// ---------------- per-bucket counting sort -> CSR rows + dinv (in-place) ----------------

__global__ void k_csr(unsigned* __restrict__ ebuf, const int* __restrict__ gCnt,
                      int2* __restrict__ rows, float* __restrict__ dinv, int n) {
    __shared__ unsigned ec[CAP];
    __shared__ int deg[KNODE];
    __shared__ int pfx[KNODE];
    int b = blockIdx.x, t = threadIdx.x;
    int cnt = gCnt[b];
    if (cnt > CAP) cnt = CAP;
    if (t < KNODE) deg[t] = 0;
    __syncthreads();
    unsigned* eb = ebuf + (size_t)b * CAP;
    for (int i = t; i < cnt; i += 256) {
        unsigned p = eb[i];
        ec[i] = p;
        atomicAdd(&deg[p >> 20], 1);
    }
    __syncthreads();
    if (t == 0) {
        int a = 0;
        for (int i = 0; i < KNODE; ++i) { pfx[i] = a; a += deg[i]; }
    }
    __syncthreads();
    if (t < KNODE) {
        int node = b * KNODE + t;
        if (node < n) {
            rows[node] = make_int2(b * CAP + pfx[t], deg[t]);
            dinv[node] = rsqrtf((float)(deg[t] + 1));
        }
    }
    if (t < KNODE) deg[t] = pfx[t];  // reuse as cursors
    __syncthreads();
    for (int i = t; i < cnt; i += 256) {
        unsigned p = ec[i];
        int pp = atomicAdd(&deg[p >> 20], 1);
        eb[pp] = p & 0xFFFFFu;  // sorted by dst-local, src only
    }
}

// ---------------- dense transforms: slice-major fp16 output [slice][N][8 half2] ----------------

__global__ void k_transform1(const float* __restrict__ x, const float* __restrict__ W,
                             const float* __restrict__ dinv, __half2* __restrict__ ts, int n) {
    __shared__ float2 sW2[3 * 16];
    int t = threadIdx.x;
    for (int i = t; i < 3 * 16; i += blockDim.x) {
        int c = i / 16, j = i % 16;
        sW2[i] = make_float2(W[c * 32 + 2 * j], W[c * 32 + 2 * j + 1]);
    }
    __syncthreads();
    int tid = blockIdx.x * blockDim.x + t;
    int node = tid >> 4;
    int j = tid & 15;
    if (node >= n) return;
    float a0 = x[(size_t)node * 3 + 0];
    float a1 = x[(size_t)node * 3 + 1];
    float a2 = x[(size_t)node * 3 + 2];
    float2 w0 = sW2[0 * 16 + j], w1 = sW2[1 * 16 + j], w2 = sW2[2 * 16 + j];
    float d = dinv[node];
    float rx = d * (a0 * w0.x + a1 * w1.x + a2 * w2.x);
    float ry = d * (a0 * w0.y + a1 * w1.y + a2 * w2.y);
    ts[((size_t)(j >> 3) * n + node) * 8 + (j & 7)] = __floats2half2_rn(rx, ry);
}

template <int IN, int OUT>
__global__ void k_transformH(const __half2* __restrict__ act, const float* __restrict__ W,
                             const float* __restrict__ dinv, __half2* __restrict__ ts, int n) {
    const int IN2 = IN / 2, OUT2 = OUT / 2;
    __shared__ float2 sW2[IN * OUT2];
    int t = threadIdx.x;
    for (int i = t; i < IN * OUT2; i += blockDim.x) {
        int c = i / OUT2, j = i % OUT2;
        sW2[i] = make_float2(W[c * OUT + 2 * j], W[c * OUT + 2 * j + 1]);
    }
    __syncthreads();
    int tid = blockIdx.x * blockDim.x + t;
    int node = tid / OUT2;
    int j = tid % OUT2;
    if (node >= n) return;
    float2 acc = make_float2(0.f, 0.f);
#pragma unroll
    for (int c2 = 0; c2 < IN2; ++c2) {
        float2 av = __half22float2(act[((size_t)(c2 >> 3) * n + node) * 8 + (c2 & 7)]);
        float2 w0 = sW2[(2 * c2) * OUT2 + j];
        float2 w1 = sW2[(2 * c2 + 1) * OUT2 + j];
        acc.x += av.x * w0.x + av.y * w1.x;
        acc.y += av.x * w0.y + av.y * w1.y;
    }
    float d = dinv[node];
    ts[((size_t)(j >> 3) * n + node) * 8 + (j & 7)] = __floats2half2_rn(d * acc.x, d * acc.y);
}

// ---------------- sliced aggregation v2: LDS edge staging + 8B gathers + work-stealing ----
// out[d] = dinv[d]*(ts[d] + sum_s ts[s]) + b ; slice = 16 features = 4 lanes x uint2

template <int NSLICE, bool RELU>
__global__ void k_aggS(const uint2* __restrict__ ts, const unsigned* __restrict__ ebuf,
                       const int* __restrict__ gCnt, const int2* __restrict__ rows,
                       const float* __restrict__ dinv, const float* __restrict__ bias,
                       uint2* __restrict__ out, int n) {
    const int XPG = 8 / NSLICE;  // buckets interleaved per 8-block row
    __shared__ unsigned eidx[CAP];
    __shared__ int cursor;
    int i = blockIdx.x;
    int xcd = i & 7;
    int slice = xcd % NSLICE;
    int b = (i >> 3) * XPG + xcd / NSLICE;
    if (b >= NB) return;
    int t = threadIdx.x;
    int cnt = gCnt[b];
    if (cnt > CAP) cnt = CAP;
    int bBase = b * CAP;
    for (int k = t; k < cnt; k += 256) eidx[k] = __builtin_nontemporal_load(&ebuf[bBase + k]);
    if (t == 0) cursor = 0;
    __syncthreads();

    const uint2* tss = ts + (size_t)slice * n * 4;
    int lane = t & 3;
    for (;;) {
        int my;
        if (lane == 0) my = atomicAdd(&cursor, 1);
        my = __shfl(my, 0, 4);
        if (my >= KNODE) break;
        int node = b * KNODE + my;
        if (node >= n) continue;
        int2 rc = rows[node];
        int ls = rc.x - bBase;
        int deg = rc.y;
        uint2 sv = tss[(size_t)node * 4 + lane];  // self-loop
        float2 a0 = __half22float2(*(__half2*)&sv.x);
        float2 a1 = __half22float2(*(__half2*)&sv.y);
        int e = 0;
        for (; e + 4 <= deg; e += 4) {
            unsigned s0 = eidx[ls + e + 0];
            unsigned s1 = eidx[ls + e + 1];
            unsigned s2 = eidx[ls + e + 2];
            unsigned s3 = eidx[ls + e + 3];
            uint2 v0 = tss[(size_t)s0 * 4 + lane];
            uint2 v1 = tss[(size_t)s1 * 4 + lane];
            uint2 v2 = tss[(size_t)s2 * 4 + lane];
            uint2 v3 = tss[(size_t)s3 * 4 + lane];
            float2 f;
            f = __half22float2(*(__half2*)&v0.x); a0.x += f.x; a0.y += f.y;
            f = __half22float2(*(__half2*)&v0.y); a1.x += f.x; a1.y += f.y;
            f = __half22float2(*(__half2*)&v1.x); a0.x += f.x; a0.y += f.y;
            f = __half22float2(*(__half2*)&v1.y); a1.x += f.x; a1.y += f.y;
            f = __half22float2(*(__half2*)&v2.x); a0.x += f.x; a0.y += f.y;
            f = __half22float2(*(__half2*)&v2.y); a1.x += f.x; a1.y += f.y;
            f = __half22float2(*(__half2*)&v3.x); a0.x += f.x; a0.y += f.y;
            f = __half22float2(*(__half2*)&v3.y); a1.x += f.x; a1.y += f.y;
        }
        for (; e < deg; ++e) {
            unsigned s = eidx[ls + e];
            uint2 v = tss[(size_t)s * 4 + lane];
            float2 f;
            f = __half22float2(*(__half2*)&v.x); a0.x += f.x; a0.y += f.y;
            f = __half22float2(*(__half2*)&v.y); a1.x += f.x; a1.y += f.y;
        }
        float dd = dinv[node];
        const float2* bp = (const float2*)(bias + slice * 16 + lane * 4);
        float2 b0 = bp[0], b1 = bp[1];
        float r0x = dd * a0.x + b0.x, r0y = dd * a0.y + b0.y;
        float r1x = dd * a1.x + b1.x, r1y = dd * a1.y + b1.y;
        if (RELU) {
            r0x = fmaxf(r0x, 0.f); r0y = fmaxf(r0y, 0.f);
            r1x = fmaxf(r1x, 0.f); r1y = fmaxf(r1y, 0.f);
        }
        __half2 o0 = __floats2half2_rn(r0x, r0y);
        __half2 o1 = __floats2half2_rn(r1x, r1y);
        uint2 w;
        w.x = *(unsigned*)&o0;
        w.y = *(unsigned*)&o1;
        out[((size_t)slice * n + node) * 4 + lane] = w;
    }
}

// ---------------- pooling over sorted batch (h slice-major fp16) ----------------

__global__ void k_pool(const __half2* __restrict__ h, const int* __restrict__ batch,
                       float* __restrict__ pooled, int n) {
    const int NBK = 32;
    int lane = threadIdx.x & 31;
    int sub = threadIdx.x >> 5;
    int n0 = (blockIdx.x * 8 + sub) * NBK;
    if (n0 >= n) return;
    int nend = n0 + NBK < n ? n0 + NBK : n;
    int s = lane >> 3, c = lane & 7;
    int fb = s * 16 + 2 * c;
    float2 acc = make_float2(0.f, 0.f);
    int gcur = batch[n0];
    for (int i = n0; i < nend; ++i) {
        int g = batch[i];
        if (g != gcur) {
            atomicAdd(&pooled[gcur * 64 + fb], acc.x);
            atomicAdd(&pooled[gcur * 64 + fb + 1], acc.y);
            acc = make_float2(0.f, 0.f);
            gcur = g;
        }
        float2 v = __half22float2(h[((size_t)s * n + i) * 8 + c]);
        acc.x += v.x;
        acc.y += v.y;
    }
    atomicAdd(&pooled[gcur * 64 + fb], acc.x);
    atomicAdd(&pooled[gcur * 64 + fb + 1], acc.y);
}

// ---------------- MLP head ----------------

__global__ void k_mlp(const float* __restrict__ pooled, const float* __restrict__ lW1,
                      const float* __restrict__ lb1, const float* __restrict__ lW2,
                      const float* __restrict__ lb2, float* __restrict__ z) {
    __shared__ float sW1[64 * 32], sW2[32 * 5], sb1[32], sb2[5];
    int t = threadIdx.x;
    for (int i = t; i < 64 * 32; i += blockDim.x) sW1[i] = lW1[i];
    for (int i = t; i < 32 * 5; i += blockDim.x) sW2[i] = lW2[i];
    if (t < 32) sb1[t] = lb1[t];
    if (t < 5) sb2[t] = lb2[t];
    __syncthreads();
    int g = blockIdx.x * blockDim.x + t;
    if (g >= N_GRAPHS) return;
    float p[64];
#pragma unroll
    for (int i = 0; i < 64; ++i) p[i] = pooled[g * 64 + i];
    float t1[32];
#pragma unroll
    for (int j = 0; j < 32; ++j) {
        float a = sb1[j];
#pragma unroll
        for (int i = 0; i < 64; ++i) a += p[i] * sW1[i * 32 + j];
        t1[j] = fmaxf(a, 0.f);
    }
#pragma unroll
    for (int c = 0; c < 5; ++c) {
        float a = sb2[c];
#pragma unroll
        for (int i = 0; i < 32; ++i) a += t1[i] * sW2[i * 5 + c];
        z[g * 5 + c] = a;
    }
}

__global__ void k_logsoftmax(const float* __restrict__ z, float* __restrict__ out) {
    __shared__ float red[512];
    int g = threadIdx.x;
#pragma unroll
    for (int c = 0; c < 5; ++c) {
        float v = z[g * 5 + c];
        red[g] = v;
        __syncthreads();
        for (int off = 256; off > 0; off >>= 1) {
            if (g < off) red[g] = fmaxf(red[g], red[g + off]);
            __syncthreads();
        }
        float m = red[0];
        __syncthreads();
        red[g] = expf(v - m);
        __syncthreads();
        for (int off = 256; off > 0; off >>= 1) {
            if (g < off) red[g] += red[g + off];
            __syncthreads();
        }
        float lse = m + logf(red[0]);
        __syncthreads();
        out[g * 5 + c] = v - lse;
    }
}

// ---------------- launch ----------------

extern "C" void kernel_launch(void* const* d_in, const int* in_sizes, int n_in,
                              void* d_out, int out_size, void* d_ws, size_t ws_size,
                              hipStream_t stream) {
    const float* x   = (const float*)d_in[0];
    const int* ei    = (const int*)d_in[1];
    const int* batch = (const int*)d_in[2];
    const float* W1  = (const float*)d_in[3];
    const float* b1  = (const float*)d_in[4];
    const float* W2  = (const float*)d_in[5];
    const float* b2  = (const float*)d_in[6];
    const float* W3  = (const float*)d_in[7];
    const float* b3  = (const float*)d_in[8];
    const float* lW1 = (const float*)d_in[9];
    const float* lb1 = (const float*)d_in[10];
    const float* lW2 = (const float*)d_in[11];
    const float* lb2 = (const float*)d_in[12];

    const int N = in_sizes[0] / 3;   // 100000
    const int E = in_sizes[1] / 2;   // 3200000
    const int* src = ei;
    const int* dst = ei + E;

    char* ws = (char*)d_ws;
    size_t off = 0;
    auto alloc = [&](size_t bytes) -> void* {
        void* p = ws + off;
        off = (off + bytes + 255) & ~(size_t)255;
        return p;
    };

    int*      gCnt   = (int*)alloc((size_t)NB * 4);
    float*    dinv   = (float*)alloc((size_t)N * 4);
    int2*     rows   = (int2*)alloc((size_t)N * 8);
    unsigned* ebuf   = (unsigned*)alloc((size_t)NB * CAP * 4);
    __half2*  bufT   = (__half2*)alloc((size_t)N * 32 * 4);
    __half2*  bufH   = (__half2*)alloc((size_t)N * 32 * 4);
    float*    pooled = (float*)alloc((size_t)N_GRAPHS * 64 * 4);
    float*    z      = (float*)alloc((size_t)N_GRAPHS * 5 * 4);

    hipMemsetAsync(gCnt, 0, (size_t)NB * 4, stream);
    hipMemsetAsync(pooled, 0, (size_t)N_GRAPHS * 64 * 4, stream);

    // CSR build via buckets
    int nPartWg = (E + EPW - 1) / EPW;
    k_part<<<nPartWg, 256, 0, stream>>>((const int4*)src, (const int4*)dst, gCnt, ebuf, E / 4);
    k_csr<<<NB, 256, 0, stream>>>(ebuf, gCnt, rows, dinv, N);

    // Layer 1: [N,3] -> [N,32], relu (2 slices of 16)
    k_transform1<<<((size_t)N * 16 + 255) / 256, 256, 0, stream>>>(x, W1, dinv, bufT, N);
    k_aggS<2, true><<<8 * ((NB + 3) / 4), 256, 0, stream>>>((const uint2*)bufT, ebuf, gCnt, rows,
                                                            dinv, b1, (uint2*)bufH, N);
    // Layer 2: [N,32] -> [N,64], relu (4 slices of 16)
    k_transformH<32, 64><<<((size_t)N * 32 + 255) / 256, 256, 0, stream>>>(bufH, W2, dinv, bufT, N);
    k_aggS<4, true><<<8 * ((NB + 1) / 2), 256, 0, stream>>>((const uint2*)bufT, ebuf, gCnt, rows,
                                                            dinv, b2, (uint2*)bufH, N);
    // Layer 3: [N,64] -> [N,64], no relu (4 slices of 16)
    k_transformH<64, 64><<<((size_t)N * 32 + 255) / 256, 256, 0, stream>>>(bufH, W3, dinv, bufT, N);
    k_aggS<4, false><<<8 * ((NB + 1) / 2), 256, 0, stream>>>((const uint2*)bufT, ebuf, gCnt, rows,
                                                             dinv, b3, (uint2*)bufH, N);

    // Pool + head
    k_pool<<<(N + 8 * 32 - 1) / (8 * 32), 256, 0, stream>>>(bufH, batch, pooled, N);
    k_mlp<<<2, 256, 0, stream>>>(pooled, lW1, lb1, lW2, lb2, z);
    k_logsoftmax<<<1, 512, 0, stream>>>(z, (float*)d_out);
}

// Round 6
// 342.439 us; speedup vs baseline: 9.1197x; 1.0927x over previous
//
#include <hip/hip_runtime.h>
#include <hip/hip_fp16.h>

#define N_GRAPHS 512
#define NB 1563        // ceil(100000/64) buckets of 64 dst nodes
#define KNODE 64
#define CAP 3072       // bucket capacity; mean 2048, sigma ~45
#define EPW 8192       // edges per partition workgroup

// ---------------- edge partition: bucket by dst>>6, packed src|dl<<20 ----------------

__global__ void k_part(const int4* __restrict__ src4, const int4* __restrict__ dst4,
                       int* __restrict__ gCnt, unsigned* __restrict__ ebuf, int E4) {
    __shared__ unsigned pos[NB];
    __shared__ int dstc[EPW];
    int t = threadIdx.x;
    int e0 = blockIdx.x * (EPW / 4);
    int cnt4 = E4 - e0 < EPW / 4 ? E4 - e0 : EPW / 4;
    for (int i = t; i < NB; i += 256) pos[i] = 0;
    __syncthreads();
    for (int i = t; i < cnt4; i += 256) {
        int4 d = dst4[e0 + i];
        dstc[4 * i + 0] = d.x; dstc[4 * i + 1] = d.y;
        dstc[4 * i + 2] = d.z; dstc[4 * i + 3] = d.w;
        atomicAdd(&pos[d.x >> 6], 1u);
        atomicAdd(&pos[d.y >> 6], 1u);
        atomicAdd(&pos[d.z >> 6], 1u);
        atomicAdd(&pos[d.w >> 6], 1u);
    }
    __syncthreads();
    for (int b = t; b < NB; b += 256) {
        unsigned c = pos[b];
        unsigned base = c ? (unsigned)atomicAdd(&gCnt[b], (int)c) : 0u;
        pos[b] = (unsigned)b * CAP + base;
    }
    __syncthreads();
    for (int i = t; i < cnt4; i += 256) {
        int4 s = src4[e0 + i];
#pragma unroll
        for (int q = 0; q < 4; ++q) {
            int d = dstc[4 * i + q];
            int sv = q == 0 ? s.x : q == 1 ? s.y : q == 2 ? s.z : s.w;
            int bkt = d >> 6;
            unsigned p = atomicAdd(&pos[bkt], 1u);
            if (p < (unsigned)(bkt + 1) * CAP)
                ebuf[p] = (unsigned)sv | ((unsigned)(d & 63) << 20);
        }
    }
}

// ---------------- per-bucket counting sort -> CSR rows + dinv (in-place) ----------------

__global__ void k_csr(unsigned* __restrict__ ebuf, const int* __restrict__ gCnt,
                      int2* __restrict__ rows, float* __restrict__ dinv, int n) {
    __shared__ unsigned ec[CAP];
    __shared__ int deg[KNODE];
    __shared__ int pfx[KNODE];
    int b = blockIdx.x, t = threadIdx.x;
    int cnt = gCnt[b];
    if (cnt > CAP) cnt = CAP;
    if (t < KNODE) deg[t] = 0;
    __syncthreads();
    unsigned* eb = ebuf + (size_t)b * CAP;
    for (int i = t; i < cnt; i += 256) {
        unsigned p = eb[i];
        ec[i] = p;
        atomicAdd(&deg[p >> 20], 1);
    }
    __syncthreads();
    if (t == 0) {
        int a = 0;
        for (int i = 0; i < KNODE; ++i) { pfx[i] = a; a += deg[i]; }
    }
    __syncthreads();
    if (t < KNODE) {
        int node = b * KNODE + t;
        if (node < n) {
            rows[node] = make_int2(b * CAP + pfx[t], deg[t]);
            dinv[node] = rsqrtf((float)(deg[t] + 1));
        }
    }
    if (t < KNODE) deg[t] = pfx[t];  // reuse as cursors
    __syncthreads();
    for (int i = t; i < cnt; i += 256) {
        unsigned p = ec[i];
        int pp = atomicAdd(&deg[p >> 20], 1);
        eb[pp] = p & 0xFFFFFu;  // sorted by dst-local, src only
    }
}

// ---------------- dense transforms: slice-major fp16 output [slice][N][8 half2] ----------------

__global__ void k_transform1(const float* __restrict__ x, const float* __restrict__ W,
                             const float* __restrict__ dinv, __half2* __restrict__ ts, int n) {
    __shared__ float2 sW2[3 * 16];
    int t = threadIdx.x;
    for (int i = t; i < 3 * 16; i += blockDim.x) {
        int c = i / 16, j = i % 16;
        sW2[i] = make_float2(W[c * 32 + 2 * j], W[c * 32 + 2 * j + 1]);
    }
    __syncthreads();
    int tid = blockIdx.x * blockDim.x + t;
    int node = tid >> 4;
    int j = tid & 15;
    if (node >= n) return;
    float a0 = x[(size_t)node * 3 + 0];
    float a1 = x[(size_t)node * 3 + 1];
    float a2 = x[(size_t)node * 3 + 2];
    float2 w0 = sW2[0 * 16 + j], w1 = sW2[1 * 16 + j], w2 = sW2[2 * 16 + j];
    float d = dinv[node];
    float rx = d * (a0 * w0.x + a1 * w1.x + a2 * w2.x);
    float ry = d * (a0 * w0.y + a1 * w1.y + a2 * w2.y);
    ts[((size_t)(j >> 3) * n + node) * 8 + (j & 7)] = __floats2half2_rn(rx, ry);
}

template <int IN, int OUT>
__global__ void k_transformH(const __half2* __restrict__ act, const float* __restrict__ W,
                             const float* __restrict__ dinv, __half2* __restrict__ ts, int n) {
    const int IN2 = IN / 2, OUT2 = OUT / 2;
    __shared__ float2 sW2[IN * OUT2];
    int t = threadIdx.x;
    for (int i = t; i < IN * OUT2; i += blockDim.x) {
        int c = i / OUT2, j = i % OUT2;
        sW2[i] = make_float2(W[c * OUT + 2 * j], W[c * OUT + 2 * j + 1]);
    }
    __syncthreads();
    int tid = blockIdx.x * blockDim.x + t;
    int node = tid / OUT2;
    int j = tid % OUT2;
    if (node >= n) return;
    float2 acc = make_float2(0.f, 0.f);
#pragma unroll
    for (int c2 = 0; c2 < IN2; ++c2) {
        float2 av = __half22float2(act[((size_t)(c2 >> 3) * n + node) * 8 + (c2 & 7)]);
        float2 w0 = sW2[(2 * c2) * OUT2 + j];
        float2 w1 = sW2[(2 * c2 + 1) * OUT2 + j];
        acc.x += av.x * w0.x + av.y * w1.x;
        acc.y += av.x * w0.y + av.y * w1.y;
    }
    float d = dinv[node];
    ts[((size_t)(j >> 3) * n + node) * 8 + (j & 7)] = __floats2half2_rn(d * acc.x, d * acc.y);
}

// ---------------- sliced aggregation v3: cached uint4 staging + 16B gathers ----------------
// out[d] = dinv[d]*(ts[d] + sum_s ts[s]) + b ; slice = 16 features = 2 lanes x uint4 (16B)
// 128 threads/block: 64 two-lane groups == 64 bucket nodes.

template <int NSLICE, bool RELU>
__global__ void k_aggS(const uint4* __restrict__ ts, const unsigned* __restrict__ ebuf,
                       const int* __restrict__ gCnt, const int2* __restrict__ rows,
                       const float* __restrict__ dinv, const float* __restrict__ bias,
                       uint4* __restrict__ out, int n) {
    const int XPG = 8 / NSLICE;  // buckets interleaved per 8-block row
    __shared__ unsigned eidx[CAP];
    __shared__ int cursor;
    int i = blockIdx.x;
    int xcd = i & 7;
    int slice = xcd % NSLICE;
    int b = (i >> 3) * XPG + xcd / NSLICE;
    if (b >= NB) return;
    int t = threadIdx.x;  // 128
    int cnt = gCnt[b];
    if (cnt > CAP) cnt = CAP;
    int bBase = b * CAP;
    const uint4* ebuf4 = (const uint4*)(ebuf + bBase);
    int cnt4 = (cnt + 3) >> 2;
    for (int k = t; k < cnt4; k += 128) ((uint4*)eidx)[k] = ebuf4[k];
    if (t == 0) cursor = 0;
    __syncthreads();

    const uint4* tss = ts + (size_t)slice * n * 2;  // 2 uint4 per node row (32 B)
    int lane = t & 1;
    for (;;) {
        int my;
        if (lane == 0) my = atomicAdd(&cursor, 1);
        my = __shfl(my, 0, 2);
        if (my >= KNODE) break;
        int node = b * KNODE + my;
        if (node >= n) continue;
        int2 rc = rows[node];
        int ls = rc.x - bBase;
        int deg = rc.y;
        float2 a0, a1, a2, a3;
        {
            uint4 sv = tss[(size_t)node * 2 + lane];  // self-loop
            a0 = __half22float2(*(__half2*)&sv.x);
            a1 = __half22float2(*(__half2*)&sv.y);
            a2 = __half22float2(*(__half2*)&sv.z);
            a3 = __half22float2(*(__half2*)&sv.w);
        }
        int e = 0;
        for (; e + 4 <= deg; e += 4) {
            unsigned s0 = eidx[ls + e + 0];
            unsigned s1 = eidx[ls + e + 1];
            unsigned s2 = eidx[ls + e + 2];
            unsigned s3 = eidx[ls + e + 3];
            uint4 v0 = tss[(size_t)s0 * 2 + lane];
            uint4 v1 = tss[(size_t)s1 * 2 + lane];
            uint4 v2 = tss[(size_t)s2 * 2 + lane];
            uint4 v3 = tss[(size_t)s3 * 2 + lane];
            float2 f;
            f = __half22float2(*(__half2*)&v0.x); a0.x += f.x; a0.y += f.y;
            f = __half22float2(*(__half2*)&v0.y); a1.x += f.x; a1.y += f.y;
            f = __half22float2(*(__half2*)&v0.z); a2.x += f.x; a2.y += f.y;
            f = __half22float2(*(__half2*)&v0.w); a3.x += f.x; a3.y += f.y;
            f = __half22float2(*(__half2*)&v1.x); a0.x += f.x; a0.y += f.y;
            f = __half22float2(*(__half2*)&v1.y); a1.x += f.x; a1.y += f.y;
            f = __half22float2(*(__half2*)&v1.z); a2.x += f.x; a2.y += f.y;
            f = __half22float2(*(__half2*)&v1.w); a3.x += f.x; a3.y += f.y;
            f = __half22float2(*(__half2*)&v2.x); a0.x += f.x; a0.y += f.y;
            f = __half22float2(*(__half2*)&v2.y); a1.x += f.x; a1.y += f.y;
            f = __half22float2(*(__half2*)&v2.z); a2.x += f.x; a2.y += f.y;
            f = __half22float2(*(__half2*)&v2.w); a3.x += f.x; a3.y += f.y;
            f = __half22float2(*(__half2*)&v3.x); a0.x += f.x; a0.y += f.y;
            f = __half22float2(*(__half2*)&v3.y); a1.x += f.x; a1.y += f.y;
            f = __half22float2(*(__half2*)&v3.z); a2.x += f.x; a2.y += f.y;
            f = __half22float2(*(__half2*)&v3.w); a3.x += f.x; a3.y += f.y;
        }
        for (; e < deg; ++e) {
            unsigned s = eidx[ls + e];
            uint4 v = tss[(size_t)s * 2 + lane];
            float2 f;
            f = __half22float2(*(__half2*)&v.x); a0.x += f.x; a0.y += f.y;
            f = __half22float2(*(__half2*)&v.y); a1.x += f.x; a1.y += f.y;
            f = __half22float2(*(__half2*)&v.z); a2.x += f.x; a2.y += f.y;
            f = __half22float2(*(__half2*)&v.w); a3.x += f.x; a3.y += f.y;
        }
        float dd = dinv[node];
        const float2* bp = (const float2*)(bias + slice * 16 + lane * 8);
        float2 b0 = bp[0], b1 = bp[1], b2 = bp[2], b3 = bp[3];
        a0.x = dd * a0.x + b0.x; a0.y = dd * a0.y + b0.y;
        a1.x = dd * a1.x + b1.x; a1.y = dd * a1.y + b1.y;
        a2.x = dd * a2.x + b2.x; a2.y = dd * a2.y + b2.y;
        a3.x = dd * a3.x + b3.x; a3.y = dd * a3.y + b3.y;
        if (RELU) {
            a0.x = fmaxf(a0.x, 0.f); a0.y = fmaxf(a0.y, 0.f);
            a1.x = fmaxf(a1.x, 0.f); a1.y = fmaxf(a1.y, 0.f);
            a2.x = fmaxf(a2.x, 0.f); a2.y = fmaxf(a2.y, 0.f);
            a3.x = fmaxf(a3.x, 0.f); a3.y = fmaxf(a3.y, 0.f);
        }
        __half2 o0 = __floats2half2_rn(a0.x, a0.y);
        __half2 o1 = __floats2half2_rn(a1.x, a1.y);
        __half2 o2 = __floats2half2_rn(a2.x, a2.y);
        __half2 o3 = __floats2half2_rn(a3.x, a3.y);
        uint4 w;
        w.x = *(unsigned*)&o0;
        w.y = *(unsigned*)&o1;
        w.z = *(unsigned*)&o2;
        w.w = *(unsigned*)&o3;
        out[((size_t)slice * n + node) * 2 + lane] = w;
    }
}

// ---------------- pooling over sorted batch (h slice-major fp16) ----------------

__global__ void k_pool(const __half2* __restrict__ h, const int* __restrict__ batch,
                       float* __restrict__ pooled, int n) {
    const int NBK = 32;
    int lane = threadIdx.x & 31;
    int sub = threadIdx.x >> 5;
    int n0 = (blockIdx.x * 8 + sub) * NBK;
    if (n0 >= n) return;
    int nend = n0 + NBK < n ? n0 + NBK : n;
    int s = lane >> 3, c = lane & 7;
    int fb = s * 16 + 2 * c;
    float2 acc = make_float2(0.f, 0.f);
    int gcur = batch[n0];
    for (int i = n0; i < nend; ++i) {
        int g = batch[i];
        if (g != gcur) {
            atomicAdd(&pooled[gcur * 64 + fb], acc.x);
            atomicAdd(&pooled[gcur * 64 + fb + 1], acc.y);
            acc = make_float2(0.f, 0.f);
            gcur = g;
        }
        float2 v = __half22float2(h[((size_t)s * n + i) * 8 + c]);
        acc.x += v.x;
        acc.y += v.y;
    }
    atomicAdd(&pooled[gcur * 64 + fb], acc.x);
    atomicAdd(&pooled[gcur * 64 + fb + 1], acc.y);
}

// ---------------- MLP head ----------------

__global__ void k_mlp(const float* __restrict__ pooled, const float* __restrict__ lW1,
                      const float* __restrict__ lb1, const float* __restrict__ lW2,
                      const float* __restrict__ lb2, float* __restrict__ z) {
    __shared__ float sW1[64 * 32], sW2[32 * 5], sb1[32], sb2[5];
    int t = threadIdx.x;
    for (int i = t; i < 64 * 32; i += blockDim.x) sW1[i] = lW1[i];
    for (int i = t; i < 32 * 5; i += blockDim.x) sW2[i] = lW2[i];
    if (t < 32) sb1[t] = lb1[t];
    if (t < 5) sb2[t] = lb2[t];
    __syncthreads();
    int g = blockIdx.x * blockDim.x + t;
    if (g >= N_GRAPHS) return;
    float p[64];
#pragma unroll
    for (int i = 0; i < 64; ++i) p[i] = pooled[g * 64 + i];
    float t1[32];
#pragma unroll
    for (int j = 0; j < 32; ++j) {
        float a = sb1[j];
#pragma unroll
        for (int i = 0; i < 64; ++i) a += p[i] * sW1[i * 32 + j];
        t1[j] = fmaxf(a, 0.f);
    }
#pragma unroll
    for (int c = 0; c < 5; ++c) {
        float a = sb2[c];
#pragma unroll
        for (int i = 0; i < 32; ++i) a += t1[i] * sW2[i * 5 + c];
        z[g * 5 + c] = a;
    }
}

__global__ void k_logsoftmax(const float* __restrict__ z, float* __restrict__ out) {
    __shared__ float red[512];
    int g = threadIdx.x;
#pragma unroll
    for (int c = 0; c < 5; ++c) {
        float v = z[g * 5 + c];
        red[g] = v;
        __syncthreads();
        for (int off = 256; off > 0; off >>= 1) {
            if (g < off) red[g] = fmaxf(red[g], red[g + off]);
            __syncthreads();
        }
        float m = red[0];
        __syncthreads();
        red[g] = expf(v - m);
        __syncthreads();
        for (int off = 256; off > 0; off >>= 1) {
            if (g < off) red[g] += red[g + off];
            __syncthreads();
        }
        float lse = m + logf(red[0]);
        __syncthreads();
        out[g * 5 + c] = v - lse;
    }
}

// ---------------- launch ----------------

extern "C" void kernel_launch(void* const* d_in, const int* in_sizes, int n_in,
                              void* d_out, int out_size, void* d_ws, size_t ws_size,
                              hipStream_t stream) {
    const float* x   = (const float*)d_in[0];
    const int* ei    = (const int*)d_in[1];
    const int* batch = (const int*)d_in[2];
    const float* W1  = (const float*)d_in[3];
    const float* b1  = (const float*)d_in[4];
    const float* W2  = (const float*)d_in[5];
    const float* b2  = (const float*)d_in[6];
    const float* W3  = (const float*)d_in[7];
    const float* b3  = (const float*)d_in[8];
    const float* lW1 = (const float*)d_in[9];
    const float* lb1 = (const float*)d_in[10];
    const float* lW2 = (const float*)d_in[11];
    const float* lb2 = (const float*)d_in[12];

    const int N = in_sizes[0] / 3;   // 100000
    const int E = in_sizes[1] / 2;   // 3200000
    const int* src = ei;
    const int* dst = ei + E;

    char* ws = (char*)d_ws;
    size_t off = 0;
    auto alloc = [&](size_t bytes) -> void* {
        void* p = ws + off;
        off = (off + bytes + 255) & ~(size_t)255;
        return p;
    };

    int*      gCnt   = (int*)alloc((size_t)NB * 4);
    float*    dinv   = (float*)alloc((size_t)N * 4);
    int2*     rows   = (int2*)alloc((size_t)N * 8);
    unsigned* ebuf   = (unsigned*)alloc((size_t)NB * CAP * 4);
    __half2*  bufT   = (__half2*)alloc((size_t)N * 32 * 4);
    __half2*  bufH   = (__half2*)alloc((size_t)N * 32 * 4);
    float*    pooled = (float*)alloc((size_t)N_GRAPHS * 64 * 4);
    float*    z      = (float*)alloc((size_t)N_GRAPHS * 5 * 4);

    hipMemsetAsync(gCnt, 0, (size_t)NB * 4, stream);
    hipMemsetAsync(pooled, 0, (size_t)N_GRAPHS * 64 * 4, stream);

    // CSR build via buckets
    int nPartWg = (E + EPW - 1) / EPW;
    k_part<<<nPartWg, 256, 0, stream>>>((const int4*)src, (const int4*)dst, gCnt, ebuf, E / 4);
    k_csr<<<NB, 256, 0, stream>>>(ebuf, gCnt, rows, dinv, N);

    // Layer 1: [N,3] -> [N,32], relu (2 slices of 16)
    k_transform1<<<((size_t)N * 16 + 255) / 256, 256, 0, stream>>>(x, W1, dinv, bufT, N);
    k_aggS<2, true><<<8 * ((NB + 3) / 4), 128, 0, stream>>>((const uint4*)bufT, ebuf, gCnt, rows,
                                                            dinv, b1, (uint4*)bufH, N);
    // Layer 2: [N,32] -> [N,64], relu (4 slices of 16)
    k_transformH<32, 64><<<((size_t)N * 32 + 255) / 256, 256, 0, stream>>>(bufH, W2, dinv, bufT, N);
    k_aggS<4, true><<<8 * ((NB + 1) / 2), 128, 0, stream>>>((const uint4*)bufT, ebuf, gCnt, rows,
                                                            dinv, b2, (uint4*)bufH, N);
    // Layer 3: [N,64] -> [N,64], no relu (4 slices of 16)
    k_transformH<64, 64><<<((size_t)N * 32 + 255) / 256, 256, 0, stream>>>(bufH, W3, dinv, bufT, N);
    k_aggS<4, false><<<8 * ((NB + 1) / 2), 128, 0, stream>>>((const uint4*)bufT, ebuf, gCnt, rows,
                                                             dinv, b3, (uint4*)bufH, N);

    // Pool + head
    k_pool<<<(N + 8 * 32 - 1) / (8 * 32), 256, 0, stream>>>(bufH, batch, pooled, N);
    k_mlp<<<2, 256, 0, stream>>>(pooled, lW1, lb1, lW2, lb2, z);
    k_logsoftmax<<<1, 512, 0, stream>>>(z, (float*)d_out);
}